// Round 4
// baseline (279.560 us; speedup 1.0000x reference)
//
#include <hip/hip_runtime.h>
#include <cmath>

#define NTOK 1024
#define HD   768
#define FF   3072
#define NE   8
#define NSLOT (NTOK * 2)
#define BK   64

typedef unsigned short u16;
typedef unsigned int   u32;
typedef __bf16 bf16x8 __attribute__((ext_vector_type(8)));
typedef float  f32x4  __attribute__((ext_vector_type(4)));

__device__ __forceinline__ u16 f2bf(float f) {
  union { float f; u32 u; } v; v.f = f;
  u32 r = v.u + 0x7FFFu + ((v.u >> 16) & 1u);
  return (u16)(r >> 16);
}

// global->LDS direct DMA, 16B per lane. LDS dest must be wave-uniform base;
// HW writes base + lane*16. Global addr is per-lane (gather OK).
__device__ __forceinline__ void load16(const void* g, void* l) {
  __builtin_amdgcn_global_load_lds(
      (const __attribute__((address_space(1))) u32*)g,
      (__attribute__((address_space(3))) u32*)l, 16, 0, 0);
}

// ---------------------------------------------------------------------------
// Weight convert + transpose: src fp32 [e][K][N] -> dst bf16 [e][N][K].
// 64x64 tiles, 256 threads.
// ---------------------------------------------------------------------------
__global__ __launch_bounds__(256) void convert_t_kernel(
    const float* __restrict__ src, u16* __restrict__ dst, int K, int N)
{
  const int e  = blockIdx.z;
  const int n0 = blockIdx.x * 64;
  const int k0 = blockIdx.y * 64;
  __shared__ u16 lt[64][65];
  const int tid = threadIdx.x;
  const int rr = tid >> 4;          // 0..15
  const int cc = (tid & 15) << 2;   // 0..60
  const float* s = src + (size_t)e * K * N;
#pragma unroll
  for (int j = 0; j < 4; ++j) {
    const int k = j * 16 + rr;
    const float4 v = *(const float4*)(s + (size_t)(k0 + k) * N + n0 + cc);
    lt[cc + 0][k] = f2bf(v.x); lt[cc + 1][k] = f2bf(v.y);
    lt[cc + 2][k] = f2bf(v.z); lt[cc + 3][k] = f2bf(v.w);
  }
  __syncthreads();
  u16* d = dst + (size_t)e * N * K;
#pragma unroll
  for (int j = 0; j < 4; ++j) {
    const int n = j * 16 + rr;
    ushort4 o;
    o.x = lt[n][cc]; o.y = lt[n][cc + 1]; o.z = lt[n][cc + 2]; o.w = lt[n][cc + 3];
    *(ushort4*)(d + (size_t)(n0 + n) * K + k0 + cc) = o;
  }
}

// ---------------------------------------------------------------------------
// Router stage A: one wave per token.
// ---------------------------------------------------------------------------
__global__ __launch_bounds__(256) void router_logits(
    const float* __restrict__ x, const float* __restrict__ rw,
    u16* __restrict__ xb, int* __restrict__ counts,
    int* __restrict__ ti, int* __restrict__ tpos, float* __restrict__ tg)
{
  __shared__ float rwt[NE * HD];
  const int tid = threadIdx.x;
  for (int i = tid; i < NE * HD; i += 256) {
    const int h = i >> 3, e = i & 7;
    rwt[e * HD + h] = rw[i];
  }
  __syncthreads();

  const int wid  = tid >> 6;
  const int lane = tid & 63;
  const int t    = blockIdx.x * 4 + wid;
  const float* xrow = x + (size_t)t * HD;
  u16* xbrow = xb + (size_t)t * HD;

  float acc[NE] = {};
#pragma unroll
  for (int j = 0; j < 12; ++j) {
    const int h = lane + j * 64;
    const float xv = xrow[h];
    xbrow[h] = f2bf(xv);
#pragma unroll
    for (int e = 0; e < NE; ++e) acc[e] += xv * rwt[e * HD + h];
  }
#pragma unroll
  for (int e = 0; e < NE; ++e) {
    float v = acc[e];
#pragma unroll
    for (int off = 32; off; off >>= 1) v += __shfl_down(v, off, 64);
    acc[e] = v;
  }

  if (lane == 0) {
    float v0 = -1e30f, v1 = -1e30f; int i0 = 0, i1 = 0;
#pragma unroll
    for (int e = 0; e < NE; ++e) {
      const float p = acc[e];
      if (p > v0) { v1 = v0; i1 = i0; v0 = p; i0 = e; }
      else if (p > v1) { v1 = p; i1 = e; }
    }
    const float e1 = expf(v1 - v0);
    const float g0 = 1.0f / (1.0f + e1);
    const float g1 = e1 / (1.0f + e1);
    const int p0 = atomicAdd(&counts[i0], 1);
    const int p1 = atomicAdd(&counts[i1], 1);
    ti[2 * t] = i0;  ti[2 * t + 1] = i1;
    tpos[2 * t] = p0; tpos[2 * t + 1] = p1;
    tg[2 * t] = g0;  tg[2 * t + 1] = g1;
  }
}

// ---------------------------------------------------------------------------
// Router stage B: prefix-sum counts -> seg, scatter slots.
// ---------------------------------------------------------------------------
__global__ __launch_bounds__(1024) void router_scatter(
    const int* __restrict__ counts, const int* __restrict__ ti,
    const int* __restrict__ tpos, const float* __restrict__ tg,
    int* __restrict__ tos, float* __restrict__ gos, int* __restrict__ seg)
{
  __shared__ int offs[NE];
  const int t = threadIdx.x;
  if (t == 0) {
    int o = 0;
    for (int e = 0; e < NE; ++e) {
      offs[e] = o; seg[e] = o; seg[NE + e] = counts[e]; o += counts[e];
    }
  }
  __syncthreads();
  const int i0 = ti[2 * t], i1 = ti[2 * t + 1];
  const int s0 = offs[i0] + tpos[2 * t];
  const int s1 = offs[i1] + tpos[2 * t + 1];
  tos[s0] = t; gos[s0] = tg[2 * t];
  tos[s1] = t; gos[s1] = tg[2 * t + 1];
}

// ---------------------------------------------------------------------------
// FFN GEMM core: 64x64 tile, BK=64, global_load_lds staging, XOR-swizzled
// unpadded LDS (physical chunk p = logical c ^ (row&7), 16B chunks).
// A: gathered rows (bf16, k-contig). B: w_t[e][n][k] bf16.
// ---------------------------------------------------------------------------

// FFN1: h = gelu(x_gather @ w1[e]) -> hbuf (bf16)
__global__ __launch_bounds__(256) void ffn1_kernel(
    const u16* __restrict__ xb, const u16* __restrict__ w1t,
    const int* __restrict__ tos, const int* __restrict__ seg,
    u16* __restrict__ hbuf)
{
  const int e   = blockIdx.z;
  const int cnt = seg[NE + e];
  const int m0  = blockIdx.y * 64;
  if (m0 >= cnt) return;
  const int start = seg[e];
  const int n0    = blockIdx.x * 64;

  __shared__ __align__(16) u16 As[64 * 64];
  __shared__ __align__(16) u16 Bs[64 * 64];
  __shared__ int toks[64];

  const int tid = threadIdx.x;
  if (tid < 64) toks[tid] = tos[start + min(m0 + tid, cnt - 1)];
  __syncthreads();

  const int lane = tid & 63;
  const int wid  = tid >> 6;

  // staging geometry: issue i covers rows wid*8 + i*32 + (lane>>3), chunk p=lane&7
  const int r0 = wid * 8 + (lane >> 3);       // issue-0 row (0..31)
  const int p  = lane & 7;
  const int c  = p ^ (r0 & 7);                // logical chunk (same for r0+32)
  const u16* ag0 = xb + (size_t)toks[r0]      * HD + c * 8;
  const u16* ag1 = xb + (size_t)toks[r0 + 32] * HD + c * 8;
  const u16* bg0 = w1t + ((size_t)e * FF + n0 + r0)      * HD + c * 8;
  const u16* bg1 = w1t + ((size_t)e * FF + n0 + r0 + 32) * HD + c * 8;
  u16* al0 = As + (wid * 8) * 64;             // wave-uniform LDS bases
  u16* al1 = As + (wid * 8 + 32) * 64;
  u16* bl0 = Bs + (wid * 8) * 64;
  u16* bl1 = Bs + (wid * 8 + 32) * 64;

  const int wm  = (wid >> 1) << 5;
  const int wn  = (wid & 1) << 5;
  const int q   = lane >> 4;
  const int r16 = lane & 15;

  f32x4 acc[2][2] = {};

  for (int k0 = 0; k0 < HD; k0 += BK) {
    load16(ag0 + k0, al0);
    load16(ag1 + k0, al1);
    load16(bg0 + k0, bl0);
    load16(bg1 + k0, bl1);
    __syncthreads();   // drains vmcnt(0) + barrier
#pragma unroll
    for (int s = 0; s < 2; ++s) {
      const int pa = ((s << 2) + q) ^ (r16 & 7);
      bf16x8 a0 = *(const bf16x8*)(&As[(wm + r16)      * 64 + (pa << 3)]);
      bf16x8 a1 = *(const bf16x8*)(&As[(wm + 16 + r16) * 64 + (pa << 3)]);
      bf16x8 b0 = *(const bf16x8*)(&Bs[(wn + r16)      * 64 + (pa << 3)]);
      bf16x8 b1 = *(const bf16x8*)(&Bs[(wn + 16 + r16) * 64 + (pa << 3)]);
      acc[0][0] = __builtin_amdgcn_mfma_f32_16x16x32_bf16(a0, b0, acc[0][0], 0, 0, 0);
      acc[0][1] = __builtin_amdgcn_mfma_f32_16x16x32_bf16(a0, b1, acc[0][1], 0, 0, 0);
      acc[1][0] = __builtin_amdgcn_mfma_f32_16x16x32_bf16(a1, b0, acc[1][0], 0, 0, 0);
      acc[1][1] = __builtin_amdgcn_mfma_f32_16x16x32_bf16(a1, b1, acc[1][1], 0, 0, 0);
    }
    __syncthreads();   // protect LDS before next slab's DMA
  }

#pragma unroll
  for (int r = 0; r < 2; ++r) {
#pragma unroll
    for (int i = 0; i < 4; ++i) {
      const int mloc = wm + r * 16 + q * 4 + i;
      if (m0 + mloc < cnt) {
        u16* drow = hbuf + (size_t)(start + m0 + mloc) * FF + n0;
#pragma unroll
        for (int cix = 0; cix < 2; ++cix) {
          float v = acc[r][cix][i];
          v = 0.5f * v * (1.0f + erff(v * 0.70710678118f));
          drow[wn + cix * 16 + r16] = f2bf(v);
        }
      }
    }
  }
}

// FFN2: out += gate * (h @ w2[e]), K-split x2, atomic fp32 accumulate.
#define KSPLIT 2
#define KSEG   (FF / KSPLIT)   // 1536

__global__ __launch_bounds__(256) void ffn2_kernel(
    const u16* __restrict__ hbuf, const u16* __restrict__ w2t,
    const int* __restrict__ tos, const float* __restrict__ gos,
    const int* __restrict__ seg, float* __restrict__ out)
{
  const int ez  = blockIdx.z;
  const int e   = ez >> 1;
  const int ks  = ez & 1;
  const int cnt = seg[NE + e];
  const int m0  = blockIdx.y * 64;
  if (m0 >= cnt) return;
  const int start = seg[e];
  const int n0    = blockIdx.x * 64;
  const int kbase = ks * KSEG;

  __shared__ __align__(16) u16 As[64 * 64];
  __shared__ __align__(16) u16 Bs[64 * 64];
  __shared__ int   toks[64];
  __shared__ float gates[64];

  const int tid = threadIdx.x;
  if (tid < 64) {
    const int idx = start + min(m0 + tid, cnt - 1);
    toks[tid]  = tos[idx];
    gates[tid] = gos[idx];
  }
  __syncthreads();

  const int lane = tid & 63;
  const int wid  = tid >> 6;

  const int r0 = wid * 8 + (lane >> 3);
  const int p  = lane & 7;
  const int c  = p ^ (r0 & 7);
  const u16* ag0 = hbuf + (size_t)(start + min(m0 + r0,      cnt - 1)) * FF + kbase + c * 8;
  const u16* ag1 = hbuf + (size_t)(start + min(m0 + r0 + 32, cnt - 1)) * FF + kbase + c * 8;
  const u16* bg0 = w2t + ((size_t)e * HD + n0 + r0)      * FF + kbase + c * 8;
  const u16* bg1 = w2t + ((size_t)e * HD + n0 + r0 + 32) * FF + kbase + c * 8;
  u16* al0 = As + (wid * 8) * 64;
  u16* al1 = As + (wid * 8 + 32) * 64;
  u16* bl0 = Bs + (wid * 8) * 64;
  u16* bl1 = Bs + (wid * 8 + 32) * 64;

  const int wm  = (wid >> 1) << 5;
  const int wn  = (wid & 1) << 5;
  const int q   = lane >> 4;
  const int r16 = lane & 15;

  f32x4 acc[2][2] = {};

  for (int k0 = 0; k0 < KSEG; k0 += BK) {
    load16(ag0 + k0, al0);
    load16(ag1 + k0, al1);
    load16(bg0 + k0, bl0);
    load16(bg1 + k0, bl1);
    __syncthreads();
#pragma unroll
    for (int s = 0; s < 2; ++s) {
      const int pa = ((s << 2) + q) ^ (r16 & 7);
      bf16x8 a0 = *(const bf16x8*)(&As[(wm + r16)      * 64 + (pa << 3)]);
      bf16x8 a1 = *(const bf16x8*)(&As[(wm + 16 + r16) * 64 + (pa << 3)]);
      bf16x8 b0 = *(const bf16x8*)(&Bs[(wn + r16)      * 64 + (pa << 3)]);
      bf16x8 b1 = *(const bf16x8*)(&Bs[(wn + 16 + r16) * 64 + (pa << 3)]);
      acc[0][0] = __builtin_amdgcn_mfma_f32_16x16x32_bf16(a0, b0, acc[0][0], 0, 0, 0);
      acc[0][1] = __builtin_amdgcn_mfma_f32_16x16x32_bf16(a0, b1, acc[0][1], 0, 0, 0);
      acc[1][0] = __builtin_amdgcn_mfma_f32_16x16x32_bf16(a1, b0, acc[1][0], 0, 0, 0);
      acc[1][1] = __builtin_amdgcn_mfma_f32_16x16x32_bf16(a1, b1, acc[1][1], 0, 0, 0);
    }
    __syncthreads();
  }

#pragma unroll
  for (int r = 0; r < 2; ++r) {
#pragma unroll
    for (int i = 0; i < 4; ++i) {
      const int mloc = wm + r * 16 + q * 4 + i;
      if (m0 + mloc < cnt) {
        const int tok  = toks[mloc];
        const float g  = gates[mloc];
        float* drow = out + (size_t)tok * HD + n0;
#pragma unroll
        for (int cix = 0; cix < 2; ++cix) {
          atomicAdd(drow + wn + cix * 16 + r16, g * acc[r][cix][i]);
        }
      }
    }
  }
}

// ---------------------------------------------------------------------------
extern "C" void kernel_launch(void* const* d_in, const int* in_sizes, int n_in,
                              void* d_out, int out_size, void* d_ws, size_t ws_size,
                              hipStream_t stream) {
  const float* x  = (const float*)d_in[0];
  const float* rw = (const float*)d_in[1];
  const float* w1 = (const float*)d_in[2];
  const float* w2 = (const float*)d_in[3];
  float* out = (float*)d_out;

  char* ws = (char*)d_ws;
  const size_t o_xb    = 0;
  const size_t o_hbuf  = o_xb + (size_t)NTOK * HD * 2;
  const size_t o_tos   = o_hbuf + (size_t)NSLOT * FF * 2;
  const size_t o_gos   = o_tos + (size_t)NSLOT * 4;
  const size_t o_seg   = o_gos + (size_t)NSLOT * 4;
  const size_t o_cnt   = o_seg + 64 * 4;
  const size_t o_ti    = o_cnt + NE * 4;
  const size_t o_tpos  = o_ti + (size_t)NSLOT * 4;
  const size_t o_tg    = o_tpos + (size_t)NSLOT * 4;
  const size_t o_w1t   = (o_tg + (size_t)NSLOT * 4 + 255) & ~(size_t)255;
  const size_t o_w2t   = o_w1t + (size_t)NE * HD * FF * 2;   // 37.75 MB each
  u16*   xb    = (u16*)(ws + o_xb);
  u16*   hbuf  = (u16*)(ws + o_hbuf);
  int*   tos   = (int*)(ws + o_tos);
  float* gos   = (float*)(ws + o_gos);
  int*   seg   = (int*)(ws + o_seg);
  int*   cnts  = (int*)(ws + o_cnt);
  int*   ti    = (int*)(ws + o_ti);
  int*   tpos  = (int*)(ws + o_tpos);
  float* tg    = (float*)(ws + o_tg);
  u16*   w1t   = (u16*)(ws + o_w1t);
  u16*   w2t   = (u16*)(ws + o_w2t);

  hipMemsetAsync(d_out, 0, (size_t)NTOK * HD * sizeof(float), stream);
  hipMemsetAsync(cnts, 0, NE * sizeof(int), stream);
  // weight convert+transpose: [e][K][N] fp32 -> [e][N][K] bf16
  hipLaunchKernelGGL(convert_t_kernel, dim3(FF / 64, HD / 64, NE), dim3(256), 0, stream,
                     w1, w1t, HD, FF);
  hipLaunchKernelGGL(convert_t_kernel, dim3(HD / 64, FF / 64, NE), dim3(256), 0, stream,
                     w2, w2t, FF, HD);
  hipLaunchKernelGGL(router_logits, dim3(NTOK / 4), dim3(256), 0, stream,
                     x, rw, xb, cnts, ti, tpos, tg);
  hipLaunchKernelGGL(router_scatter, dim3(1), dim3(1024), 0, stream,
                     cnts, ti, tpos, tg, tos, gos, seg);
  hipLaunchKernelGGL(ffn1_kernel, dim3(FF / 64, NTOK / 64, NE), dim3(256), 0, stream,
                     xb, w1t, tos, seg, hbuf);
  hipLaunchKernelGGL(ffn2_kernel, dim3(HD / 64, NTOK / 64, NE * KSPLIT), dim3(256), 0, stream,
                     hbuf, w2t, tos, gos, seg, out);
}